// Round 5
// baseline (527.272 us; speedup 1.0000x reference)
//
#include <hip/hip_runtime.h>
#include <stdint.h>

#define E_TOTAL   500000
#define NODE_DIM  128
#define EDGE_DIM  64
#define IN_DIM    192
#define OUT_DIM_  128
#define LN_EPS    1e-5f
#define NTILES    ((E_TOTAL + 63) / 64)   // 7813 tiles of 64 rows

typedef __attribute__((ext_vector_type(8))) short  short8;
typedef __attribute__((ext_vector_type(4))) float  floatx4;
typedef __attribute__((ext_vector_type(4))) unsigned int uintx4;

union Frag { short8 s; uintx4 u; };

// HW packed f32->bf16 (RNE), 1 instruction.
__device__ __forceinline__ unsigned int cvtpk(float a, float b) {
    unsigned int r;
    asm("v_cvt_pk_bf16_f32 %0, %1, %2" : "=v"(r) : "v"(a), "v"(b));
    return r;
}
// Raw transcendentals (~1 ulp) — tolerance is bf16-scale (absmax 0.0078).
__device__ __forceinline__ float fexp2(float x) {
    float r; asm("v_exp_f32 %0, %1" : "=v"(r) : "v"(x)); return r;
}
__device__ __forceinline__ float frcp(float x) {
    float r; asm("v_rcp_f32 %0, %1" : "=v"(r) : "v"(x)); return r;
}
__device__ __forceinline__ float frsq(float x) {
    float r; asm("v_rsq_f32 %0, %1" : "=v"(r) : "v"(x)); return r;
}
// silu = y * rcp(1 + 2^(-y*log2e)) : 5 VALU (2 trans)
__device__ __forceinline__ float silu(float y) {
    return y * frcp(1.0f + fexp2(y * -1.44269504f));
}

// TRANSPOSED-C DATAFLOW (round 4->5 structural change):
// mfma(W_frag, x_frag) instead of mfma(x_frag, W_frag). A-frag layout
// (lane: A[row=l15][k=quad*8+i]) and B-frag (B[k=quad*8+i][col=l15]) are
// duals, so the SAME staged bytes serve either role. C becomes:
//   lane (quad,l15) holds h[edge_row = l15][col = t*16 + quad*4 + j].
// => LN reduce = lane-local 32 + 2 shfl rounds (was 4 rounds x 4 vals);
// => hstage written as 4x ds_write_b128 per lane via k-permutation
//    sigma(c) = quad*32 + t*4 + j (W2 frags built with sigma^-1 at init —
//    legal since GEMM2 sums over k);
// => epilogue rows are lane-major: 8x b128 ost writes, full-line stores.
//
// LDS: W1 frags 49152 + ws 4*1088*4=17408 + params 2048 = 68608 B
// -> 2 blocks/CU, 8 waves/CU = 2 waves/SIMD.
// ws[wave]: bf16 hstage [16 rows][136 shorts] (272 B/row) during GEMM2,
// then fp32 ost [16 rows][68 floats] (272 B/row) per epilogue half-pass.
// Stride 272 B: ds b128 start-banks = 4*(l15+quad) mod 32 -> 8 groups x 8
// lanes = the pattern already measured cheap in rounds 1-4.
__launch_bounds__(256, 2)
__global__ void edge_mlp_kernel(
    const float* __restrict__ src,   // E x 128
    const float* __restrict__ edg,   // E x 64
    const float* __restrict__ W1,    // 192 x 128 (K x N)
    const float* __restrict__ b1,    // 128
    const float* __restrict__ gam,   // 128
    const float* __restrict__ bet,   // 128
    const float* __restrict__ W2,    // 128 x 128 (K x N)
    const float* __restrict__ b2,    // 128
    float* __restrict__ out)         // E x 128
{
    __shared__ uintx4 w1f[48 * 64];                        // 48 frags (s=0..5, t=0..7)
    __shared__ __align__(16) float ws[4][1088];            // per-wave scratch
    __shared__ float pl[512];                              // b1 | gamma | beta | b2

    const int tid  = threadIdx.x;
    const int lane = tid & 63;
    const int wave = tid >> 6;
    const int quad = lane >> 4;
    const int l15  = lane & 15;
    const int q4   = quad * 4;

    // ---- stage W1 frags: frag f=s*8+t, lane holds W1[s*32+quad*8+j][t*16+l15]
    #pragma unroll
    for (int i = 0; i < 12; ++i) {
        int f = wave + 4 * i;
        int s = f >> 3, t = f & 7;
        const float* wp = W1 + (size_t)(s * 32 + quad * 8) * OUT_DIM_ + t * 16 + l15;
        uintx4 v;
        v.x = cvtpk(wp[0],            wp[OUT_DIM_]);
        v.y = cvtpk(wp[2 * OUT_DIM_], wp[3 * OUT_DIM_]);
        v.z = cvtpk(wp[4 * OUT_DIM_], wp[5 * OUT_DIM_]);
        v.w = cvtpk(wp[6 * OUT_DIM_], wp[7 * OUT_DIM_]);
        w1f[f * 64 + lane] = v;
    }
    // ---- params into LDS
    pl[tid]       = (tid < 128) ? b1[tid]  : gam[tid - 128];
    pl[256 + tid] = (tid < 128) ? bet[tid] : b2[tid - 128];

    // ---- W2 frags in registers, built with sigma^-1 row addressing:
    // frag (s2,t): lane needs A[row=l15][k=quad*8+i] = W2[sig^-1(s2*32+quad*8+i)][t*16+l15]
    // sig^-1(k): c = ((k>>2)&7)*16 + (k>>5)*4 + (k&3)
    // => i=0..3: W2 row = 32*quad + 4*s2 + i ; i=4..7: row = 32*quad + 16 + 4*s2 + (i-4)
    Frag w2r[32];
    #pragma unroll
    for (int f = 0; f < 32; ++f) {
        int s2 = f >> 3, t = f & 7;
        const float* wp = W2 + (size_t)(32 * quad + 4 * s2) * OUT_DIM_ + t * 16 + l15;
        w2r[f].u.x = cvtpk(wp[0],              wp[OUT_DIM_]);
        w2r[f].u.y = cvtpk(wp[2 * OUT_DIM_],   wp[3 * OUT_DIM_]);
        w2r[f].u.z = cvtpk(wp[16 * OUT_DIM_],  wp[17 * OUT_DIM_]);
        w2r[f].u.w = cvtpk(wp[18 * OUT_DIM_],  wp[19 * OUT_DIM_]);
    }
    __syncthreads();

    unsigned short* hst = (unsigned short*)&ws[wave][0];   // [16][136] shorts
    float*          ost = &ws[wave][0];                    // [16][68] floats

    // ---- software-pipelined A: prefetch tile0 into registers
    int tile = blockIdx.x;
    floatx4 nx[12];
    {
        int r = tile * 64 + wave * 16 + l15;
        int rc = r < E_TOTAL ? r : (E_TOTAL - 1);
        const float* sp = src + (size_t)rc * NODE_DIM + quad * 8;
        const float* ep = edg + (size_t)rc * EDGE_DIM + quad * 8;
        #pragma unroll
        for (int s = 0; s < 4; ++s) {
            nx[2 * s]     = *(const floatx4*)(sp + s * 32);
            nx[2 * s + 1] = *(const floatx4*)(sp + s * 32 + 4);
        }
        #pragma unroll
        for (int s = 0; s < 2; ++s) {
            nx[8 + 2 * s] = *(const floatx4*)(ep + s * 32);
            nx[9 + 2 * s] = *(const floatx4*)(ep + s * 32 + 4);
        }
    }

    for (; tile < NTILES; tile += gridDim.x) {
        const int rbase = tile * 64 + wave * 16;

        // ---- init acc with b1 broadcast: acc[t][j] accumulates h[l15][t*16+q4+j]
        floatx4 acc[8];
        #pragma unroll
        for (int t = 0; t < 8; ++t)
            acc[t] = *(const floatx4*)&pl[t * 16 + q4];

        // ---- GEMM1 (swapped): mfma(W1_frag, x_frag)
        #pragma unroll
        for (int s = 0; s < 6; ++s) {
            floatx4 x0 = nx[2 * s];
            floatx4 x1 = nx[2 * s + 1];
            Frag a;
            a.u.x = cvtpk(x0.x, x0.y);
            a.u.y = cvtpk(x0.z, x0.w);
            a.u.z = cvtpk(x1.x, x1.y);
            a.u.w = cvtpk(x1.z, x1.w);
            #pragma unroll
            for (int t = 0; t < 8; ++t) {
                Frag w; w.u = w1f[(s * 8 + t) * 64 + lane];
                acc[t] = __builtin_amdgcn_mfma_f32_16x16x32_bf16(w.s, a.s, acc[t], 0, 0, 0);
            }
        }

        // ---- issue next tile's A-loads; latency hides under LN+GEMM2+stores
        {
            int tn = tile + gridDim.x;
            if (tn < NTILES) {
                int r = tn * 64 + wave * 16 + l15;
                int rc = r < E_TOTAL ? r : (E_TOTAL - 1);
                const float* sp = src + (size_t)rc * NODE_DIM + quad * 8;
                const float* ep = edg + (size_t)rc * EDGE_DIM + quad * 8;
                #pragma unroll
                for (int s = 0; s < 4; ++s) {
                    nx[2 * s]     = *(const floatx4*)(sp + s * 32);
                    nx[2 * s + 1] = *(const floatx4*)(sp + s * 32 + 4);
                }
                #pragma unroll
                for (int s = 0; s < 2; ++s) {
                    nx[8 + 2 * s] = *(const floatx4*)(ep + s * 32);
                    nx[9 + 2 * s] = *(const floatx4*)(ep + s * 32 + 4);
                }
            }
        }

        // ---- LayerNorm: lane-local partial over 32 cols + 2 shfl rounds
        // (4 lanes share row l15: lane ids l15 + {0,16,32,48})
        float S1 = 0.0f, S2 = 0.0f;
        #pragma unroll
        for (int t = 0; t < 8; ++t) {
            #pragma unroll
            for (int j = 0; j < 4; ++j) {
                float h = acc[t][j];
                S1 += h;
                S2 += h * h;
            }
        }
        S1 += __shfl_xor(S1, 16, 64);
        S2 += __shfl_xor(S2, 16, 64);
        S1 += __shfl_xor(S1, 32, 64);
        S2 += __shfl_xor(S2, 32, 64);
        float mu = S1 * (1.0f / 128.0f);
        float var = S2 * (1.0f / 128.0f) - mu * mu;
        float rs = frsq(var + LN_EPS);

        // ---- normalize + SiLU + bf16-pack, k-contiguous per lane:
        // value (t,j) -> k = quad*32 + t*4 + j; chunk u covers t=2u,2u+1.
        #pragma unroll
        for (int u = 0; u < 4; ++u) {
            uintx4 d;
            #pragma unroll
            for (int h2 = 0; h2 < 2; ++h2) {
                int t = 2 * u + h2;
                floatx4 g4 = *(const floatx4*)&pl[128 + t * 16 + q4];
                floatx4 bt4 = *(const floatx4*)&pl[256 + t * 16 + q4];
                float y0, y1, y2, y3;
                {
                    float gs = rs * g4.x;
                    y0 = silu(__builtin_fmaf(acc[t][0], gs, __builtin_fmaf(-mu, gs, bt4.x)));
                }
                {
                    float gs = rs * g4.y;
                    y1 = silu(__builtin_fmaf(acc[t][1], gs, __builtin_fmaf(-mu, gs, bt4.y)));
                }
                {
                    float gs = rs * g4.z;
                    y2 = silu(__builtin_fmaf(acc[t][2], gs, __builtin_fmaf(-mu, gs, bt4.z)));
                }
                {
                    float gs = rs * g4.w;
                    y3 = silu(__builtin_fmaf(acc[t][3], gs, __builtin_fmaf(-mu, gs, bt4.w)));
                }
                if (h2 == 0) { d.x = cvtpk(y0, y1); d.y = cvtpk(y2, y3); }
                else         { d.z = cvtpk(y0, y1); d.w = cvtpk(y2, y3); }
            }
            *(uintx4*)&hst[l15 * 136 + quad * 32 + u * 8] = d;
        }

        // ---- init GEMM2 acc with b2
        #pragma unroll
        for (int t = 0; t < 8; ++t)
            acc[t] = *(const floatx4*)&pl[384 + t * 16 + q4];

        // ---- GEMM2 (swapped): mfma(W2_frag, h_frag); h-read is b128,
        // byte pattern identical to the round-1..4 proven-cheap one.
        #pragma unroll
        for (int s2 = 0; s2 < 4; ++s2) {
            Frag hf;
            hf.u = *(const uintx4*)&hst[l15 * 136 + s2 * 32 + quad * 8];
            #pragma unroll
            for (int t = 0; t < 8; ++t) {
                acc[t] = __builtin_amdgcn_mfma_f32_16x16x32_bf16(w2r[s2 * 8 + t].s, hf.s, acc[t], 0, 0, 0);
            }
        }

        // ---- SiLU + staged full-line stores. Pass p covers cols 64p..64p+63
        // (t = 4p..4p+3): lane writes 4x b128 to ost[16][68]; read-back
        // instr v covers rows 4v..4v+3 x 64 cols = 2 full 128B lines/row.
        #pragma unroll
        for (int p = 0; p < 2; ++p) {
            #pragma unroll
            for (int tt = 0; tt < 4; ++tt) {
                int t = p * 4 + tt;
                floatx4 y;
                y.x = silu(acc[t][0]);
                y.y = silu(acc[t][1]);
                y.z = silu(acc[t][2]);
                y.w = silu(acc[t][3]);
                *(floatx4*)&ost[l15 * 68 + tt * 16 + q4] = y;
            }
            #pragma unroll
            for (int v = 0; v < 4; ++v) {
                int row = v * 4 + (lane >> 4);
                int c4  = lane & 15;
                int grow = rbase + row;
                if (grow < E_TOTAL) {
                    floatx4 val = *(const floatx4*)&ost[row * 68 + c4 * 4];
                    *(floatx4*)(out + (size_t)grow * OUT_DIM_ + p * 64 + c4 * 4) = val;
                }
            }
        }
    }
}

extern "C" void kernel_launch(void* const* d_in, const int* in_sizes, int n_in,
                              void* d_out, int out_size, void* d_ws, size_t ws_size,
                              hipStream_t stream) {
    const float* src = (const float*)d_in[0];
    const float* edg = (const float*)d_in[1];
    const float* W1  = (const float*)d_in[2];
    const float* b1  = (const float*)d_in[3];
    const float* gam = (const float*)d_in[4];
    const float* bet = (const float*)d_in[5];
    const float* W2  = (const float*)d_in[6];
    const float* b2  = (const float*)d_in[7];
    float* out = (float*)d_out;

    edge_mlp_kernel<<<512, 256, 0, stream>>>(src, edg, W1, b1, gam, bet, W2, b2, out);
}